// Round 1
// baseline (290.289 us; speedup 1.0000x reference)
//
#include <hip/hip_runtime.h>
#include <hip/hip_bf16.h>
#include <math.h>

#define N_PTS 100000
#define P_PROP 256
#define R_FEAT 256
#define NCLS 21          // C + 1
#define NSEG 8           // segments per proposal (grid = P*NSEG blocks)
#define SEG_LEN (N_PTS / NSEG)   // 12500 exactly
#define CHUNK 1024       // points compacted per pass (4 ballots per wave)

// ---------------- Kernel 1: masked partial sums per (segment, proposal) ----
// block = 256 threads; thread t owns feature channel t.
// blockIdx.x = p*NSEG + s
__global__ __launch_bounds__(256) void roi_partial_kernel(
    const float* __restrict__ proposals,   // (P,6)
    const float* __restrict__ xyz,         // (N,3)
    const float* __restrict__ feats,       // (N,R)
    float* __restrict__ psums,             // (NSEG,P,R)
    float* __restrict__ pcounts)           // (NSEG,P)
{
    const int p = blockIdx.x >> 3;
    const int s = blockIdx.x & (NSEG - 1);
    const int t = threadIdx.x;

    const float cx = proposals[p * 6 + 0];
    const float cy = proposals[p * 6 + 1];
    const float cz = proposals[p * 6 + 2];
    const float hx = proposals[p * 6 + 3] * 0.5f;
    const float hy = proposals[p * 6 + 4] * 0.5f;
    const float hz = proposals[p * 6 + 5] * 0.5f;
    const float lox = cx - hx, hix = cx + hx;
    const float loy = cy - hy, hiy = cy + hy;
    const float loz = cz - hz, hiz = cz + hz;

    __shared__ int list[CHUNK];
    __shared__ int cnt;

    const int n0 = s * SEG_LEN;
    const int n1 = n0 + SEG_LEN;

    float acc = 0.0f;
    int total = 0;

    for (int base = n0; base < n1; base += CHUNK) {
        if (t == 0) cnt = 0;
        __syncthreads();

        const int lim = min(base + CHUNK, n1);
        for (int i = base + t; i < lim; i += 256) {
            const float x = xyz[i * 3 + 0];
            const float y = xyz[i * 3 + 1];
            const float z = xyz[i * 3 + 2];
            const bool in = (x >= lox) & (x <= hix) &
                            (y >= loy) & (y <= hiy) &
                            (z >= loz) & (z <= hiz);
            const unsigned long long b = __ballot(in);
            const int lane = t & 63;
            const int prefix = __popcll(b & ((1ull << lane) - 1ull));
            const int nb = __popcll(b);
            int baseoff = 0;
            if (lane == 0 && nb) baseoff = atomicAdd(&cnt, nb);
            baseoff = __shfl(baseoff, 0, 64);
            if (in) list[baseoff + prefix] = i;
        }
        __syncthreads();

        const int m = cnt;
        total += m;
        int j = 0;
        for (; j + 4 <= m; j += 4) {
            const int i0 = list[j + 0];
            const int i1 = list[j + 1];
            const int i2 = list[j + 2];
            const int i3 = list[j + 3];
            const float f0 = feats[i0 * R_FEAT + t];
            const float f1 = feats[i1 * R_FEAT + t];
            const float f2 = feats[i2 * R_FEAT + t];
            const float f3 = feats[i3 * R_FEAT + t];
            acc += f0; acc += f1; acc += f2; acc += f3;
        }
        for (; j < m; ++j) {
            acc += feats[list[j] * R_FEAT + t];
        }
        __syncthreads();   // protect list/cnt before next chunk
    }

    psums[(s * P_PROP + p) * R_FEAT + t] = acc;
    if (t == 0) pcounts[s * P_PROP + p] = (float)total;
}

// ---------------- Kernel 2: reduce partials + both logit heads -------------
// grid = P blocks, block = 256 threads (thread t = channel t for reduction)
__global__ __launch_bounds__(256) void head_logits_kernel(
    const float* __restrict__ psums,     // (NSEG,P,R)
    const float* __restrict__ pcounts,   // (NSEG,P)
    const float* __restrict__ Wc,        // (R,21)
    const float* __restrict__ bc,        // (21)
    const float* __restrict__ Wo,        // (R,21)
    const float* __restrict__ bo,        // (21)
    float* __restrict__ cls_logits,      // (P,21)
    float* __restrict__ obj_logits)      // (P,21)
{
    const int p = blockIdx.x;
    const int t = threadIdx.x;

    __shared__ float roi[R_FEAT];

    float sum = 0.0f;
#pragma unroll
    for (int s = 0; s < NSEG; ++s)
        sum += psums[(s * P_PROP + p) * R_FEAT + t];

    float c = 0.0f;
#pragma unroll
    for (int s = 0; s < NSEG; ++s)
        c += pcounts[s * P_PROP + p];
    c = fmaxf(c, 1.0f);

    roi[t] = sum / c;
    __syncthreads();

    if (t < NCLS) {
        float acc = bc[t];
        for (int r = 0; r < R_FEAT; ++r)
            acc = fmaf(roi[r], Wc[r * NCLS + t], acc);
        cls_logits[p * NCLS + t] = acc;
    } else if (t >= 64 && t < 64 + NCLS) {
        const int cc = t - 64;
        float acc = bo[cc];
        for (int r = 0; r < R_FEAT; ++r)
            acc = fmaf(roi[r], Wo[r * NCLS + cc], acc);
        obj_logits[p * NCLS + cc] = acc;
    }
}

// ---------------- Kernel 3: softmaxes + elementwise product ----------------
// single block, 256 threads; thread t = proposal t
__global__ __launch_bounds__(256) void softmax_mul_kernel(
    const float* __restrict__ cls_logits,  // (P,21)
    const float* __restrict__ obj_logits,  // (P,21)
    float* __restrict__ out)               // (P,21)
{
    const int t = threadIdx.x;

    __shared__ float objl[P_PROP][NCLS];
    __shared__ float colmax[NCLS];
    __shared__ float colsum[NCLS];

    float cl[NCLS], ob[NCLS];
#pragma unroll
    for (int c = 0; c < NCLS; ++c) {
        cl[c] = cls_logits[t * NCLS + c];
        ob[c] = obj_logits[t * NCLS + c];
        objl[t][c] = ob[c];
    }
    __syncthreads();

    if (t < NCLS) {
        float m = -INFINITY;
        for (int p = 0; p < P_PROP; ++p) m = fmaxf(m, objl[p][t]);
        float sacc = 0.0f;
        for (int p = 0; p < P_PROP; ++p) sacc += expf(objl[p][t] - m);
        colmax[t] = m;
        colsum[t] = sacc;
    }

    // row softmax (cls) locally
    float m = cl[0];
#pragma unroll
    for (int c = 1; c < NCLS; ++c) m = fmaxf(m, cl[c]);
    float e[NCLS];
    float sacc = 0.0f;
#pragma unroll
    for (int c = 0; c < NCLS; ++c) { e[c] = expf(cl[c] - m); sacc += e[c]; }
    const float inv = 1.0f / sacc;

    __syncthreads();

#pragma unroll
    for (int c = 0; c < NCLS; ++c) {
        const float cp = e[c] * inv;
        const float op = expf(ob[c] - colmax[c]) / colsum[c];
        out[t * NCLS + c] = cp * op;
    }
}

// ---------------- launch ----------------------------------------------------
extern "C" void kernel_launch(void* const* d_in, const int* in_sizes, int n_in,
                              void* d_out, int out_size, void* d_ws, size_t ws_size,
                              hipStream_t stream) {
    const float* proposals = (const float*)d_in[0];  // (256,6)
    const float* xyz       = (const float*)d_in[1];  // (100000,3)
    const float* feats     = (const float*)d_in[2];  // (100000,256)
    const float* Wc        = (const float*)d_in[3];  // (256,21)
    const float* bc        = (const float*)d_in[4];  // (21)
    const float* Wo        = (const float*)d_in[5];  // (256,21)
    const float* bo        = (const float*)d_in[6];  // (21)
    float* out = (float*)d_out;                      // (256,21)

    char* ws = (char*)d_ws;
    float* psums   = (float*)(ws);                             // 8*256*256*4 = 2 MiB
    float* pcounts = (float*)(ws + 2097152);                   // 8 KiB
    float* clsl    = (float*)(ws + 2097152 + 8192);            // 21504 B
    float* objl    = (float*)(ws + 2097152 + 8192 + 21504);    // 21504 B

    roi_partial_kernel<<<P_PROP * NSEG, 256, 0, stream>>>(proposals, xyz, feats,
                                                          psums, pcounts);
    head_logits_kernel<<<P_PROP, 256, 0, stream>>>(psums, pcounts, Wc, bc, Wo, bo,
                                                   clsl, objl);
    softmax_mul_kernel<<<1, 256, 0, stream>>>(clsl, objl, out);
}

// Round 2
// 238.745 us; speedup vs baseline: 1.2159x; 1.2159x over previous
//
#include <hip/hip_runtime.h>
#include <hip/hip_bf16.h>
#include <math.h>

#define N_PTS 100000
#define P_PROP 256
#define R_FEAT 256
#define NCLS 21          // C + 1
#define NSEG 16          // segments per proposal (grid = P*NSEG blocks)
#define SEG_LEN (N_PTS / NSEG)   // 6250 exactly
#define CHUNK 2048       // points compacted per pass

// ---------------- Kernel 1: masked partial sums per (segment, proposal) ----
// block = 256 threads = 4 waves.
// Mask phase: thread-per-point ballot compaction into LDS list.
// Gather phase: wave w takes compacted rows j ≡ w (mod 4); each lane loads
// float4 (16 B) so one wave covers a full 1 KB feature row per iteration.
// blockIdx.x = p*NSEG + s
__global__ __launch_bounds__(256) void roi_partial_kernel(
    const float* __restrict__ proposals,   // (P,6)
    const float* __restrict__ xyz,         // (N,3)
    const float* __restrict__ feats,       // (N,R)
    float* __restrict__ psums,             // (NSEG,P,R)
    float* __restrict__ pcounts)           // (NSEG,P)
{
    const int p = blockIdx.x >> 4;
    const int s = blockIdx.x & (NSEG - 1);
    const int t = threadIdx.x;
    const int wave = t >> 6;
    const int lane = t & 63;

    const float cx = proposals[p * 6 + 0];
    const float cy = proposals[p * 6 + 1];
    const float cz = proposals[p * 6 + 2];
    const float hx = proposals[p * 6 + 3] * 0.5f;
    const float hy = proposals[p * 6 + 4] * 0.5f;
    const float hz = proposals[p * 6 + 5] * 0.5f;
    const float lox = cx - hx, hix = cx + hx;
    const float loy = cy - hy, hiy = cy + hy;
    const float loz = cz - hz, hiz = cz + hz;

    __shared__ int list[CHUNK];
    __shared__ float red[4][R_FEAT];
    __shared__ int cnt;

    const int n0 = s * SEG_LEN;
    const int n1 = n0 + SEG_LEN;

    float4 acc = make_float4(0.f, 0.f, 0.f, 0.f);
    int total = 0;

    for (int base = n0; base < n1; base += CHUNK) {
        if (t == 0) cnt = 0;
        __syncthreads();

        const int lim = min(base + CHUNK, n1);
        for (int i = base + t; i < lim; i += 256) {
            const float x = xyz[i * 3 + 0];
            const float y = xyz[i * 3 + 1];
            const float z = xyz[i * 3 + 2];
            const bool in = (x >= lox) & (x <= hix) &
                            (y >= loy) & (y <= hiy) &
                            (z >= loz) & (z <= hiz);
            const unsigned long long b = __ballot(in);
            const int prefix = __popcll(b & ((1ull << lane) - 1ull));
            const int nb = __popcll(b);
            int baseoff = 0;
            if (lane == 0 && nb) baseoff = atomicAdd(&cnt, nb);
            baseoff = __shfl(baseoff, 0, 64);
            if (in) list[baseoff + prefix] = i;
        }
        __syncthreads();

        const int m = cnt;
        total += m;

        // gather: wave-strided rows, float4 per lane, unroll x4
        const float* __restrict__ fbase = feats;
        int j = wave;
        for (; j + 12 < m; j += 16) {
            const int r0 = list[j];
            const int r1 = list[j + 4];
            const int r2 = list[j + 8];
            const int r3 = list[j + 12];
            const float4 f0 = *(const float4*)(fbase + (size_t)r0 * R_FEAT + lane * 4);
            const float4 f1 = *(const float4*)(fbase + (size_t)r1 * R_FEAT + lane * 4);
            const float4 f2 = *(const float4*)(fbase + (size_t)r2 * R_FEAT + lane * 4);
            const float4 f3 = *(const float4*)(fbase + (size_t)r3 * R_FEAT + lane * 4);
            acc.x += f0.x; acc.y += f0.y; acc.z += f0.z; acc.w += f0.w;
            acc.x += f1.x; acc.y += f1.y; acc.z += f1.z; acc.w += f1.w;
            acc.x += f2.x; acc.y += f2.y; acc.z += f2.z; acc.w += f2.w;
            acc.x += f3.x; acc.y += f3.y; acc.z += f3.z; acc.w += f3.w;
        }
        for (; j < m; j += 4) {
            const int r = list[j];
            const float4 f = *(const float4*)(fbase + (size_t)r * R_FEAT + lane * 4);
            acc.x += f.x; acc.y += f.y; acc.z += f.z; acc.w += f.w;
        }
        __syncthreads();   // protect list/cnt before next chunk
    }

    // cross-wave reduction: wave w's lane L holds channels 4L..4L+3
    *(float4*)(&red[wave][lane * 4]) = acc;
    __syncthreads();

    const float sum = red[0][t] + red[1][t] + red[2][t] + red[3][t];
    psums[(s * P_PROP + p) * R_FEAT + t] = sum;
    if (t == 0) pcounts[s * P_PROP + p] = (float)total;
}

// ---------------- Kernel 2: reduce partials + both logit heads -------------
// grid = P blocks, block = 256 threads.
// Phase 1: thread t = channel t, reduce over NSEG segments.
// Phase 2: thread (chunk = t>>6, c2 = t&63): c2<21 -> cls class c2,
//          21<=c2<42 -> obj class c2-21; each sums 64 r-values, LDS-reduce.
__global__ __launch_bounds__(256) void head_logits_kernel(
    const float* __restrict__ psums,     // (NSEG,P,R)
    const float* __restrict__ pcounts,   // (NSEG,P)
    const float* __restrict__ Wc,        // (R,21)
    const float* __restrict__ bc,        // (21)
    const float* __restrict__ Wo,        // (R,21)
    const float* __restrict__ bo,        // (21)
    float* __restrict__ cls_logits,      // (P,21)
    float* __restrict__ obj_logits)      // (P,21)
{
    const int p = blockIdx.x;
    const int t = threadIdx.x;

    __shared__ float roi[R_FEAT];
    __shared__ float part[4][64];

    float sum = 0.0f;
#pragma unroll
    for (int s = 0; s < NSEG; ++s)
        sum += psums[(s * P_PROP + p) * R_FEAT + t];

    float c = 0.0f;
#pragma unroll
    for (int s = 0; s < NSEG; ++s)
        c += pcounts[s * P_PROP + p];
    c = fmaxf(c, 1.0f);

    roi[t] = sum / c;
    __syncthreads();

    const int c2 = t & 63;
    const int chunk = t >> 6;
    float acc = 0.0f;
    if (c2 < 2 * NCLS) {
        const float* __restrict__ W = (c2 < NCLS) ? Wc : Wo;
        const int cc = (c2 < NCLS) ? c2 : c2 - NCLS;
        const int r0 = chunk * 64;
#pragma unroll
        for (int r = 0; r < 64; ++r)
            acc = fmaf(roi[r0 + r], W[(r0 + r) * NCLS + cc], acc);
    }
    part[chunk][c2] = acc;
    __syncthreads();

    if (t < 2 * NCLS) {
        const float v = part[0][t] + part[1][t] + part[2][t] + part[3][t];
        if (t < NCLS) cls_logits[p * NCLS + t] = v + bc[t];
        else          obj_logits[p * NCLS + (t - NCLS)] = v + bo[t - NCLS];
    }
}

// ---------------- Kernel 3: softmaxes + elementwise product ----------------
// single block, 256 threads; thread t = proposal t for the row softmax;
// (g = t>>5, cc = t&31) for the 8-way-parallel column reductions.
__global__ __launch_bounds__(256) void softmax_mul_kernel(
    const float* __restrict__ cls_logits,  // (P,21)
    const float* __restrict__ obj_logits,  // (P,21)
    float* __restrict__ out)               // (P,21)
{
    const int t = threadIdx.x;
    const int cc = t & 31;
    const int g = t >> 5;

    __shared__ float objl[P_PROP][NCLS];
    __shared__ float red[8][32];
    __shared__ float colmax[32];
    __shared__ float colsum[32];

    float cl[NCLS], ob[NCLS];
#pragma unroll
    for (int c = 0; c < NCLS; ++c) {
        cl[c] = cls_logits[t * NCLS + c];
        ob[c] = obj_logits[t * NCLS + c];
        objl[t][c] = ob[c];
    }
    __syncthreads();

    // column max (over proposals), 8 groups of 32
    float m = -INFINITY;
    if (cc < NCLS) {
        const int p0 = g * 32;
        for (int p = p0; p < p0 + 32; ++p) m = fmaxf(m, objl[p][cc]);
    }
    red[g][cc] = m;
    __syncthreads();
    if (t < NCLS) {
        float mm = red[0][t];
#pragma unroll
        for (int gg = 1; gg < 8; ++gg) mm = fmaxf(mm, red[gg][t]);
        colmax[t] = mm;
    }
    __syncthreads();

    // column sum of exp
    float sc = 0.0f;
    if (cc < NCLS) {
        const float mm = colmax[cc];
        const int p0 = g * 32;
        for (int p = p0; p < p0 + 32; ++p) sc += expf(objl[p][cc] - mm);
    }
    red[g][cc] = sc;
    __syncthreads();
    if (t < NCLS) {
        float ss = red[0][t];
#pragma unroll
        for (int gg = 1; gg < 8; ++gg) ss += red[gg][t];
        colsum[t] = ss;
    }

    // row softmax (cls) in registers meanwhile
    float rm = cl[0];
#pragma unroll
    for (int c = 1; c < NCLS; ++c) rm = fmaxf(rm, cl[c]);
    float e[NCLS];
    float rs = 0.0f;
#pragma unroll
    for (int c = 0; c < NCLS; ++c) { e[c] = expf(cl[c] - rm); rs += e[c]; }
    const float inv = 1.0f / rs;

    __syncthreads();

#pragma unroll
    for (int c = 0; c < NCLS; ++c) {
        const float cp = e[c] * inv;
        const float op = expf(ob[c] - colmax[c]) / colsum[c];
        out[t * NCLS + c] = cp * op;
    }
}

// ---------------- launch ----------------------------------------------------
extern "C" void kernel_launch(void* const* d_in, const int* in_sizes, int n_in,
                              void* d_out, int out_size, void* d_ws, size_t ws_size,
                              hipStream_t stream) {
    const float* proposals = (const float*)d_in[0];  // (256,6)
    const float* xyz       = (const float*)d_in[1];  // (100000,3)
    const float* feats     = (const float*)d_in[2];  // (100000,256)
    const float* Wc        = (const float*)d_in[3];  // (256,21)
    const float* bc        = (const float*)d_in[4];  // (21)
    const float* Wo        = (const float*)d_in[5];  // (256,21)
    const float* bo        = (const float*)d_in[6];  // (21)
    float* out = (float*)d_out;                      // (256,21)

    char* ws = (char*)d_ws;
    float* psums   = (float*)(ws);                             // 16*256*256*4 = 4 MiB
    float* pcounts = (float*)(ws + 4194304);                   // 16 KiB
    float* clsl    = (float*)(ws + 4194304 + 16384);           // 21504 B
    float* objl    = (float*)(ws + 4194304 + 16384 + 21504);   // 21504 B

    roi_partial_kernel<<<P_PROP * NSEG, 256, 0, stream>>>(proposals, xyz, feats,
                                                          psums, pcounts);
    head_logits_kernel<<<P_PROP, 256, 0, stream>>>(psums, pcounts, Wc, bc, Wo, bo,
                                                   clsl, objl);
    softmax_mul_kernel<<<1, 256, 0, stream>>>(clsl, objl, out);
}

// Round 3
// 217.949 us; speedup vs baseline: 1.3319x; 1.0954x over previous
//
#include <hip/hip_runtime.h>
#include <hip/hip_bf16.h>
#include <math.h>

#define N_PTS 100000
#define P_PROP 256
#define R_FEAT 256
#define NCLS 21          // C + 1
#define NSEG 32          // segments; window = 3125 rows * 1KB = 3.125 MB < 4 MiB XCD-L2
#define SEG_LEN (N_PTS / NSEG)   // 3125 exactly
#define LIST_MAX 3136    // >= SEG_LEN, multiple of 64

// ---------------- Kernel 1: masked partial sums per (segment, proposal) ----
// grid = 8192 blocks, XCD-swizzled: bid = q*2048 + p*8 + x, s = q*8 + x.
// Under bid%8 -> XCD round-robin, all 256 proposals of a segment co-reside on
// one XCD whose L2 caches that segment's 3.125 MB feature window; each row's
// ~8-proposal reuse is then served from L2 instead of L3.
// block = 256 threads = 4 waves. Mask: ballot-compaction of the whole segment
// into LDS (single pass). Gather: wave w takes rows j≡w (mod 4), float4/lane,
// 8 rows in flight.
__global__ __launch_bounds__(256) void roi_partial_kernel(
    const float* __restrict__ proposals,   // (P,6)
    const float* __restrict__ xyz,         // (N,3)
    const float* __restrict__ feats,       // (N,R)
    float* __restrict__ psums,             // (NSEG,P,R)
    float* __restrict__ pcounts)           // (NSEG,P)
{
    const int bid = blockIdx.x;
    const int x = bid & 7;
    const int p = (bid >> 3) & (P_PROP - 1);
    const int q = bid >> 11;
    const int s = q * 8 + x;

    const int t = threadIdx.x;
    const int wave = t >> 6;
    const int lane = t & 63;

    const float cx = proposals[p * 6 + 0];
    const float cy = proposals[p * 6 + 1];
    const float cz = proposals[p * 6 + 2];
    const float hx = proposals[p * 6 + 3] * 0.5f;
    const float hy = proposals[p * 6 + 4] * 0.5f;
    const float hz = proposals[p * 6 + 5] * 0.5f;
    const float lox = cx - hx, hix = cx + hx;
    const float loy = cy - hy, hiy = cy + hy;
    const float loz = cz - hz, hiz = cz + hz;

    __shared__ int list[LIST_MAX];
    __shared__ float red[4][R_FEAT];
    __shared__ int cnt;

    if (t == 0) cnt = 0;
    __syncthreads();

    const int n0 = s * SEG_LEN;
    const int n1 = n0 + SEG_LEN;

    // ---- mask + compact (single pass over the segment) ----
    for (int i = n0 + t; i < n1; i += 256) {
        const float xx = xyz[i * 3 + 0];
        const float yy = xyz[i * 3 + 1];
        const float zz = xyz[i * 3 + 2];
        const bool in = (xx >= lox) & (xx <= hix) &
                        (yy >= loy) & (yy <= hiy) &
                        (zz >= loz) & (zz <= hiz);
        const unsigned long long b = __ballot(in);
        const int prefix = __popcll(b & ((1ull << lane) - 1ull));
        const int nb = __popcll(b);
        int baseoff = 0;
        if (lane == 0 && nb) baseoff = atomicAdd(&cnt, nb);
        baseoff = __shfl(baseoff, 0, 64);
        if (in) list[baseoff + prefix] = i;
    }
    __syncthreads();

    const int m = cnt;

    // ---- gather: wave-strided rows, float4 per lane, 8 rows in flight ----
    float4 acc = make_float4(0.f, 0.f, 0.f, 0.f);
    int j = wave;
    for (; j + 28 < m; j += 32) {
        int r[8];
#pragma unroll
        for (int u = 0; u < 8; ++u) r[u] = list[j + 4 * u];
        float4 f[8];
#pragma unroll
        for (int u = 0; u < 8; ++u)
            f[u] = *(const float4*)(feats + (size_t)r[u] * R_FEAT + lane * 4);
#pragma unroll
        for (int u = 0; u < 8; ++u) {
            acc.x += f[u].x; acc.y += f[u].y; acc.z += f[u].z; acc.w += f[u].w;
        }
    }
    for (; j < m; j += 4) {
        const int r = list[j];
        const float4 f = *(const float4*)(feats + (size_t)r * R_FEAT + lane * 4);
        acc.x += f.x; acc.y += f.y; acc.z += f.z; acc.w += f.w;
    }

    // ---- cross-wave reduction: wave w's lane L holds channels 4L..4L+3 ----
    *(float4*)(&red[wave][lane * 4]) = acc;
    __syncthreads();

    const float sum = red[0][t] + red[1][t] + red[2][t] + red[3][t];
    psums[(s * P_PROP + p) * R_FEAT + t] = sum;
    if (t == 0) pcounts[s * P_PROP + p] = (float)m;
}

// ---------------- Kernel 2: reduce partials + both logit heads -------------
// grid = P blocks, block = 256 threads.
// Phase 1: thread t = channel t, reduce over NSEG segments.
// Phase 2: thread (chunk = t>>6, c2 = t&63): c2<21 -> cls class c2,
//          21<=c2<42 -> obj class c2-21; each sums 64 r-values, LDS-reduce.
__global__ __launch_bounds__(256) void head_logits_kernel(
    const float* __restrict__ psums,     // (NSEG,P,R)
    const float* __restrict__ pcounts,   // (NSEG,P)
    const float* __restrict__ Wc,        // (R,21)
    const float* __restrict__ bc,        // (21)
    const float* __restrict__ Wo,        // (R,21)
    const float* __restrict__ bo,        // (21)
    float* __restrict__ cls_logits,      // (P,21)
    float* __restrict__ obj_logits)      // (P,21)
{
    const int p = blockIdx.x;
    const int t = threadIdx.x;

    __shared__ float roi[R_FEAT];
    __shared__ float part[4][64];

    float sum = 0.0f;
#pragma unroll
    for (int s = 0; s < NSEG; ++s)
        sum += psums[(s * P_PROP + p) * R_FEAT + t];

    float c = 0.0f;
#pragma unroll
    for (int s = 0; s < NSEG; ++s)
        c += pcounts[s * P_PROP + p];
    c = fmaxf(c, 1.0f);

    roi[t] = sum / c;
    __syncthreads();

    const int c2 = t & 63;
    const int chunk = t >> 6;
    float acc = 0.0f;
    if (c2 < 2 * NCLS) {
        const float* __restrict__ W = (c2 < NCLS) ? Wc : Wo;
        const int cc = (c2 < NCLS) ? c2 : c2 - NCLS;
        const int r0 = chunk * 64;
#pragma unroll
        for (int r = 0; r < 64; ++r)
            acc = fmaf(roi[r0 + r], W[(r0 + r) * NCLS + cc], acc);
    }
    part[chunk][c2] = acc;
    __syncthreads();

    if (t < 2 * NCLS) {
        const float v = part[0][t] + part[1][t] + part[2][t] + part[3][t];
        if (t < NCLS) cls_logits[p * NCLS + t] = v + bc[t];
        else          obj_logits[p * NCLS + (t - NCLS)] = v + bo[t - NCLS];
    }
}

// ---------------- Kernel 3: softmaxes + elementwise product ----------------
// single block, 256 threads; thread t = proposal t for the row softmax;
// (g = t>>5, cc = t&31) for the 8-way-parallel column reductions.
__global__ __launch_bounds__(256) void softmax_mul_kernel(
    const float* __restrict__ cls_logits,  // (P,21)
    const float* __restrict__ obj_logits,  // (P,21)
    float* __restrict__ out)               // (P,21)
{
    const int t = threadIdx.x;
    const int cc = t & 31;
    const int g = t >> 5;

    __shared__ float objl[P_PROP][NCLS];
    __shared__ float red[8][32];
    __shared__ float colmax[32];
    __shared__ float colsum[32];

    float cl[NCLS], ob[NCLS];
#pragma unroll
    for (int c = 0; c < NCLS; ++c) {
        cl[c] = cls_logits[t * NCLS + c];
        ob[c] = obj_logits[t * NCLS + c];
        objl[t][c] = ob[c];
    }
    __syncthreads();

    // column max (over proposals), 8 groups of 32
    float m = -INFINITY;
    if (cc < NCLS) {
        const int p0 = g * 32;
        for (int p = p0; p < p0 + 32; ++p) m = fmaxf(m, objl[p][cc]);
    }
    red[g][cc] = m;
    __syncthreads();
    if (t < NCLS) {
        float mm = red[0][t];
#pragma unroll
        for (int gg = 1; gg < 8; ++gg) mm = fmaxf(mm, red[gg][t]);
        colmax[t] = mm;
    }
    __syncthreads();

    // column sum of exp
    float sc = 0.0f;
    if (cc < NCLS) {
        const float mm = colmax[cc];
        const int p0 = g * 32;
        for (int p = p0; p < p0 + 32; ++p) sc += expf(objl[p][cc] - mm);
    }
    red[g][cc] = sc;
    __syncthreads();
    if (t < NCLS) {
        float ss = red[0][t];
#pragma unroll
        for (int gg = 1; gg < 8; ++gg) ss += red[gg][t];
        colsum[t] = ss;
    }

    // row softmax (cls) in registers meanwhile
    float rm = cl[0];
#pragma unroll
    for (int c = 1; c < NCLS; ++c) rm = fmaxf(rm, cl[c]);
    float e[NCLS];
    float rs = 0.0f;
#pragma unroll
    for (int c = 0; c < NCLS; ++c) { e[c] = expf(cl[c] - rm); rs += e[c]; }
    const float inv = 1.0f / rs;

    __syncthreads();

#pragma unroll
    for (int c = 0; c < NCLS; ++c) {
        const float cp = e[c] * inv;
        const float op = expf(ob[c] - colmax[c]) / colsum[c];
        out[t * NCLS + c] = cp * op;
    }
}

// ---------------- launch ----------------------------------------------------
extern "C" void kernel_launch(void* const* d_in, const int* in_sizes, int n_in,
                              void* d_out, int out_size, void* d_ws, size_t ws_size,
                              hipStream_t stream) {
    const float* proposals = (const float*)d_in[0];  // (256,6)
    const float* xyz       = (const float*)d_in[1];  // (100000,3)
    const float* feats     = (const float*)d_in[2];  // (100000,256)
    const float* Wc        = (const float*)d_in[3];  // (256,21)
    const float* bc        = (const float*)d_in[4];  // (21)
    const float* Wo        = (const float*)d_in[5];  // (256,21)
    const float* bo        = (const float*)d_in[6];  // (21)
    float* out = (float*)d_out;                      // (256,21)

    char* ws = (char*)d_ws;
    float* psums   = (float*)(ws);                              // 32*256*256*4 = 8 MiB
    float* pcounts = (float*)(ws + 8388608);                    // 32 KiB
    float* clsl    = (float*)(ws + 8388608 + 32768);            // 21504 B
    float* objl    = (float*)(ws + 8388608 + 32768 + 21504);    // 21504 B

    roi_partial_kernel<<<P_PROP * NSEG, 256, 0, stream>>>(proposals, xyz, feats,
                                                          psums, pcounts);
    head_logits_kernel<<<P_PROP, 256, 0, stream>>>(psums, pcounts, Wc, bc, Wo, bo,
                                                   clsl, objl);
    softmax_mul_kernel<<<1, 256, 0, stream>>>(clsl, objl, out);
}